// Round 1
// 427.698 us; speedup vs baseline: 1.0133x; 1.0133x over previous
//
#include <hip/hip_runtime.h>
#include <hip/hip_bf16.h>

#define B_ROWS 256
#define S_SUP  65536
#define D_DIM  768
#define QSZ    512
#define NCHUNK 12          // 768 / 64
#define CHUNK_BYTES 32768  // 256 rows * 64 k * 2 B (A chunk, bf16 swizzled)
#define BTILE_BYTES 16384  // 64 cols * 64 k * 4 B (B chunk, fp32 swizzled)

typedef short bf16x8 __attribute__((ext_vector_type(8)));
typedef float f32x4  __attribute__((ext_vector_type(4)));

__device__ __forceinline__ bf16x8 cvt8(float4 a, float4 b) {
  bf16x8 r;
  r[0] = (short)(__float_as_uint(a.x) >> 16);
  r[1] = (short)(__float_as_uint(a.y) >> 16);
  r[2] = (short)(__float_as_uint(a.z) >> 16);
  r[3] = (short)(__float_as_uint(a.w) >> 16);
  r[4] = (short)(__float_as_uint(b.x) >> 16);
  r[5] = (short)(__float_as_uint(b.y) >> 16);
  r[6] = (short)(__float_as_uint(b.z) >> 16);
  r[7] = (short)(__float_as_uint(b.w) >> 16);
  return r;
}

__device__ __forceinline__ void gl_lds16(const void* g, void* l) {
  __builtin_amdgcn_global_load_lds(
      (const __attribute__((address_space(1))) unsigned int*)g,
      (__attribute__((address_space(3))) unsigned int*)l, 16, 0, 0);
}

// block-wide sum (float), result broadcast to all 256 threads (4 waves)
__device__ __forceinline__ float block_sum(float v) {
  __shared__ float tmp[4];
  #pragma unroll
  for (int m = 32; m >= 1; m >>= 1) v += __shfl_xor(v, m, 64);
  __syncthreads();
  if ((threadIdx.x & 63) == 0) tmp[threadIdx.x >> 6] = v;
  __syncthreads();
  return tmp[0] + tmp[1] + tmp[2] + tmp[3];
}

__device__ __forceinline__ double block_sum_d(double v) {
  __shared__ double tmp[4];
  #pragma unroll
  for (int m = 32; m >= 1; m >>= 1) v += __shfl_xor(v, m, 64);
  __syncthreads();
  if ((threadIdx.x & 63) == 0) tmp[threadIdx.x >> 6] = v;
  __syncthreads();
  return tmp[0] + tmp[1] + tmp[2] + tmp[3];
}

// ---- kernel 0: zero accumulators ----
__global__ __launch_bounds__(256) void init_kernel(unsigned long long* gmax, double* bden) {
  int t = threadIdx.x;
  gmax[t] = 0ull;
  for (int i = t; i < 3 * B_ROWS; i += 256) bden[i] = 0.0;
}

// ---- kernel 1: augs[j-1] = normalize(V[j]*L); j==0 -> org_bf16 (swizzled chunk image) ----
// org_bf16 layout: chunk c (k in [64c,64c+64)) is a 32 KB image: row r's 8 16B-groups,
// group jg stored at slot (jg ^ (r&7)).  ushort index = c*16384 + r*64 + slot*8 + e.
__global__ __launch_bounds__(256) void prep_kernel(const float* __restrict__ V,
                                                   const float* __restrict__ L,
                                                   unsigned short* __restrict__ orgb,
                                                   float* __restrict__ augs) {
  int jb = blockIdx.x;            // 0..1023
  int j = jb >> 8, b = jb & 255;
  int tid = threadIdx.x;
  const float* v = V + ((size_t)j * B_ROWS + b) * D_DIM;
  const float* l = L + (size_t)b * D_DIM;
  float p[3]; float ssq = 0.f;
  #pragma unroll
  for (int i = 0; i < 3; ++i) {
    int k = tid + 256 * i;
    p[i] = v[k] * l[k];
    ssq += p[i] * p[i];
  }
  ssq = block_sum(ssq);
  float inv = 1.0f / fmaxf(sqrtf(ssq), 1e-12f);
  if (j == 0) {
    #pragma unroll
    for (int i = 0; i < 3; ++i) {
      int k = tid + 256 * i;
      unsigned short hv = (unsigned short)(__float_as_uint(p[i] * inv) >> 16);
      int c = k >> 6, kk = k & 63, jg = kk >> 3, e = kk & 7;
      orgb[c * 16384 + b * 64 + ((jg ^ (b & 7)) << 3) + e] = hv;
    }
  } else {
    float* dst = augs + ((size_t)(j - 1) * B_ROWS + b) * D_DIM;
    #pragma unroll
    for (int i = 0; i < 3; ++i) dst[tid + 256 * i] = p[i] * inv;
  }
}

// ---- kernel 2: sim = org @ sf^T (bf16 MFMA, LDS-staged A AND B), per-row argmax ----
// B tile: 64 support rows x 64 k, fp32, staged to LDS via global_load_lds with
// pre-swizzled SOURCE (group g stored at slot g ^ (s&15)); read applies same XOR.
__global__ __launch_bounds__(256) void sim_argmax_kernel(const unsigned short* __restrict__ orgb,
                                                         const float* __restrict__ sf,
                                                         unsigned long long* __restrict__ gmax) {
  const int tid  = threadIdx.x;
  const int w    = tid >> 6;          // wave 0..3
  const int lid  = tid & 63;
  const int quad = lid >> 4;          // 0..3
  const int r15  = lid & 15;          // 0..15
  const int s_rel = w * 16 + r15;     // col within block tile (0..63)
  const int s_col = blockIdx.x * 64 + s_rel;
  const int s0    = blockIdx.x * 64;

  // A chunk [0,32768) + B tile [32768,49152); epilogue smax/sidx overlaid after last barrier
  __shared__ __align__(16) char smem[CHUNK_BYTES + BTILE_BYTES];

  f32x4 acc[16];
  #pragma unroll
  for (int t = 0; t < 16; ++t) acc[t] = (f32x4){0.f, 0.f, 0.f, 0.f};

  const char* gsrc_base = (const char*)orgb;

  for (int c = 0; c < NCHUNK; ++c) {
    // stage A chunk c: wave w copies bytes [w*8192, w*8192+8192) verbatim
    {
      const char* g = gsrc_base + c * CHUNK_BYTES + w * 8192 + lid * 16;
      char* ldst = smem + w * 8192;
      #pragma unroll
      for (int i = 0; i < 8; ++i)
        gl_lds16(g + i * 1024, ldst + i * 1024);
    }
    // stage B tile: 64 rows x 64 k fp32 = 16 KB = 1024 16B-groups, 4 per thread.
    // dest linear (group p at byte 32768+16p); source group = slot ^ (s&15)
    {
      #pragma unroll
      for (int i = 0; i < 4; ++i) {
        int p    = i * 256 + tid;
        int s    = p >> 4;
        int slot = p & 15;
        int g    = slot ^ (s & 15);
        const float* bsrc = sf + (size_t)(s0 + s) * D_DIM + c * 64 + g * 4;
        gl_lds16(bsrc, smem + CHUNK_BYTES + i * 4096 + w * 1024);
      }
    }
    __syncthreads();

    const char* brow = smem + CHUNK_BYTES + s_rel * 256;
    const int   bm   = s_rel & 15;     // == r15
    #pragma unroll
    for (int k1 = 0; k1 < 2; ++k1) {
      // B frag: k = k1*32 + quad*8 + [0..8) -> groups gg, gg+1 (4 floats each)
      int gg = k1 * 8 + quad * 2;
      float4 b0 = *(const float4*)(brow + (((gg    ) ^ bm) << 4));
      float4 b1 = *(const float4*)(brow + (((gg + 1) ^ bm) << 4));
      bf16x8 bf = cvt8(b0, b1);
      // A from LDS: row r = r15+16t, group jg = k1*4+quad, slot = jg ^ (r15&7)
      int abase = r15 * 128 + (((k1 * 4 + quad) ^ (r15 & 7)) << 4);
      #pragma unroll
      for (int t = 0; t < 16; ++t) {
        bf16x8 af = *(const bf16x8*)(smem + abase + t * 2048);
        acc[t] = __builtin_amdgcn_mfma_f32_16x16x32_bf16(af, bf, acc[t], 0, 0, 0);
      }
    }
    __syncthreads();
  }

  // epilogue: overlay reduction arrays on smem (all LDS reads of tiles are done,
  // last __syncthreads of the loop guarantees it)
  float* smax = (float*)smem;                // 4*256 floats = 4 KB
  int*   sidx = (int*)(smem + 4096);         // 4*256 ints   = 4 KB
  #pragma unroll
  for (int t = 0; t < 16; ++t) {
    #pragma unroll
    for (int r = 0; r < 4; ++r) {
      float v = acc[t][r];
      int   idx = s_col;
      #pragma unroll
      for (int m = 1; m < 16; m <<= 1) {     // reduce over the 16 n-lanes
        float ov = __shfl_xor(v, m, 64);
        int   oi = __shfl_xor(idx, m, 64);
        if (ov > v || (ov == v && oi < idx)) { v = ov; idx = oi; }
      }
      if (r15 == 0) {
        int b = 16 * t + 4 * quad + r;       // C/D layout: row = quad*4+reg
        smax[w * 256 + b] = v;
        sidx[w * 256 + b] = idx;
      }
    }
  }
  __syncthreads();
  {
    int b = tid;
    float v = smax[b]; int idx = sidx[b];
    #pragma unroll
    for (int w2 = 1; w2 < 4; ++w2) {
      float ov = smax[w2 * 256 + b]; int oi = sidx[w2 * 256 + b];
      if (ov > v || (ov == v && oi < idx)) { v = ov; idx = oi; }
    }
    unsigned u = __float_as_uint(v);
    unsigned key = (u & 0x80000000u) ? ~u : (u | 0x80000000u);
    unsigned long long packed = ((unsigned long long)key << 32) |
                                (unsigned long long)(0xFFFFFFFFu - (unsigned)idx);
    atomicMax(gmax + b, packed);
  }
}

// ---- kernel 3: nn = normalize(sf[nn_idx]); nnT; num = dot(nn, augs[0][b]) / T ----
__global__ __launch_bounds__(256) void nn_kernel(const unsigned long long* __restrict__ gmax,
                                                 const float* __restrict__ sf,
                                                 const float* __restrict__ augs,
                                                 float* __restrict__ nn,
                                                 float* __restrict__ nnT,
                                                 float* __restrict__ num) {
  int b = blockIdx.x, tid = threadIdx.x;
  int idx = (int)(0xFFFFFFFFu - (unsigned)(gmax[b] & 0xFFFFFFFFull));
  const float* row = sf + (size_t)idx * D_DIM;
  float p[3]; float ssq = 0.f;
  #pragma unroll
  for (int i = 0; i < 3; ++i) { p[i] = row[tid + 256 * i]; ssq += p[i] * p[i]; }
  ssq = block_sum(ssq);
  float inv = 1.0f / fmaxf(sqrtf(ssq), 1e-12f);
  const float* a0 = augs + (size_t)b * D_DIM;    // augs[0][b]
  float dot = 0.f;
  #pragma unroll
  for (int i = 0; i < 3; ++i) {
    int k = tid + 256 * i;
    float nv = p[i] * inv;
    nn[(size_t)b * D_DIM + k] = nv;
    nnT[(size_t)k * B_ROWS + b] = nv;
    dot += nv * a0[k];
  }
  dot = block_sum(dot);
  if (tid == 0) num[b] = dot * 10.0f;            // 1/TEMP = 10
}

// ---- kernel 4: batch_den[j][b] += sum_i exp(10*dot(nn_b, aug_ji)) (double acc) ----
__global__ __launch_bounds__(256) void bden_kernel(const float* __restrict__ augs,
                                                   const float* __restrict__ nnT,
                                                   double* __restrict__ bden) {
  int jc = blockIdx.x;                 // 0..191
  int j = jc >> 6, c = jc & 63;
  int i0 = c * 4;
  __shared__ float s_aug[4 * D_DIM];
  const float* src = augs + ((size_t)j * B_ROWS + i0) * D_DIM;
  for (int idx = threadIdx.x; idx < 4 * D_DIM; idx += 256) s_aug[idx] = src[idx];
  __syncthreads();
  int b = threadIdx.x;
  float a0 = 0.f, a1 = 0.f, a2 = 0.f, a3 = 0.f;
  for (int k = 0; k < D_DIM; ++k) {
    float nv = nnT[(size_t)k * B_ROWS + b];
    a0 += nv * s_aug[k];
    a1 += nv * s_aug[D_DIM + k];
    a2 += nv * s_aug[2 * D_DIM + k];
    a3 += nv * s_aug[3 * D_DIM + k];
  }
  double v = exp((double)a0 * 10.0) + exp((double)a1 * 10.0) +
             exp((double)a2 * 10.0) + exp((double)a3 * 10.0);
  atomicAdd(&bden[j * B_ROWS + b], v);
}

// ---- kernel 5: GPS-filtered queue denominator (16 lanes per row, double exp-sum) ----
__global__ __launch_bounds__(256) void queue_kernel(const float* __restrict__ gps,
                                                    const float* __restrict__ sgps,
                                                    const float* __restrict__ sf,
                                                    const float* __restrict__ nn,
                                                    double* __restrict__ qden) {
  int b = blockIdx.x, tid = threadIdx.x;
  int w = tid >> 6, lane = tid & 63;
  __shared__ int qidx[QSZ];
  __shared__ int s_count;
  __shared__ int s_wcnt[4];
  __shared__ __align__(16) float s_nn[D_DIM];
  __shared__ double s_gsum[16];
  for (int k = tid; k < D_DIM; k += 256) s_nn[k] = nn[(size_t)b * D_DIM + k];
  if (tid == 0) s_count = 0;
  __syncthreads();

  const float r = 0.017453292519943295f;
  float lat1 = gps[b * 2 + 0] * r, lon1 = gps[b * 2 + 1] * r;
  float cl1 = cosf(lat1);
  int base = 0;
  while (true) {
    int count = s_count;
    if (count >= QSZ || base >= S_SUP) break;
    int s = base + tid;
    float lat2 = sgps[s * 2 + 0] * r, lon2 = sgps[s * 2 + 1] * r;
    float sdlat = sinf((lat2 - lat1) * 0.5f);
    float sdlon = sinf((lon2 - lon1) * 0.5f);
    float a = sdlat * sdlat + cl1 * cosf(lat2) * sdlon * sdlon;
    a = fminf(fmaxf(a, 0.f), 1.f);
    float d = 2.0f * 6371.0088f * asinf(sqrtf(a));
    bool valid = d > 25.0f;

    unsigned long long m = __ballot(valid);
    int wc = __popcll(m);
    if (lane == 0) s_wcnt[w] = wc;
    __syncthreads();
    int wbase = count;
    for (int i = 0; i < w; ++i) wbase += s_wcnt[i];
    int pos = wbase + __popcll(m & ((1ull << lane) - 1ull));
    if (valid && pos < QSZ) qidx[pos] = s;
    __syncthreads();
    if (tid == 0) {
      int total = s_wcnt[0] + s_wcnt[1] + s_wcnt[2] + s_wcnt[3];
      s_count = min(QSZ, count + total);
    }
    base += 256;
    __syncthreads();
  }
  int count = s_count;

  // phase 2: 16 lanes per row, 16 rows in flight per block
  int g  = lane >> 4;                  // group 0..3 within wave
  int l2 = lane & 15;
  double acc = 0.0;
  const float4* nn4 = (const float4*)s_nn;
  for (int q = w * 4 + g; q < count; q += 16) {
    const float4* row = (const float4*)(sf + (size_t)qidx[q] * D_DIM);
    float dot = 0.f;
    #pragma unroll
    for (int i = 0; i < 12; ++i) {
      float4 a = row[l2 + 16 * i];
      float4 nv = nn4[l2 + 16 * i];
      dot += a.x * nv.x + a.y * nv.y + a.z * nv.z + a.w * nv.w;
    }
    #pragma unroll
    for (int m2 = 8; m2 >= 1; m2 >>= 1) dot += __shfl_xor(dot, m2, 16);
    if (l2 == 0) acc += exp((double)dot * 10.0);
  }
  if (l2 == 0) s_gsum[w * 4 + g] = acc;
  __syncthreads();
  if (tid == 0) {
    double t = (double)(QSZ - count);
    #pragma unroll
    for (int i = 0; i < 16; ++i) t += s_gsum[i];
    qden[b] = t;
  }
}

// ---- kernel 6: final scalar loss (double) ----
__global__ __launch_bounds__(256) void loss_kernel(const float* __restrict__ num,
                                                   const double* __restrict__ bden,
                                                   const double* __restrict__ qden,
                                                   float* __restrict__ out) {
  int b = threadIdx.x;
  double q = qden[b];
  double n = (double)num[b];
  double t = 0.0;
  #pragma unroll
  for (int j = 0; j < 3; ++j) t += n - log(bden[j * B_ROWS + b] + q);
  t = block_sum_d(t);
  if (b == 0) out[0] = (float)(-t / 256.0);
}

extern "C" void kernel_launch(void* const* d_in, const int* in_sizes, int n_in,
                              void* d_out, int out_size, void* d_ws, size_t ws_size,
                              hipStream_t stream) {
  const float* V    = (const float*)d_in[0];   // (4,256,768)
  const float* L    = (const float*)d_in[1];   // (256,768)
  const float* gps  = (const float*)d_in[2];   // (256,2)
  const float* sf   = (const float*)d_in[3];   // (65536,768)
  const float* sgps = (const float*)d_in[4];   // (65536,2)
  float* out = (float*)d_out;

  char* ws = (char*)d_ws;
  size_t off = 0;
  unsigned short* orgb = (unsigned short*)(ws + off); off += 393216;  // 12*32KB bf16 swizzled
  float* augs = (float*)(ws + off); off += 2359296;                   // 3*256*768*4
  float* nn   = (float*)(ws + off); off += 786432;
  float* nnT  = (float*)(ws + off); off += 786432;
  float* num  = (float*)(ws + off); off += 1024;                      // 256*4
  double* bden = (double*)(ws + off); off += 6144;                    // 3*256*8
  double* qden = (double*)(ws + off); off += 2048;                    // 256*8
  unsigned long long* gmax = (unsigned long long*)(ws + off); off += 2048;

  init_kernel<<<1, 256, 0, stream>>>(gmax, bden);
  prep_kernel<<<1024, 256, 0, stream>>>(V, L, orgb, augs);
  sim_argmax_kernel<<<S_SUP / 64, 256, 0, stream>>>(orgb, sf, gmax);
  nn_kernel<<<B_ROWS, 256, 0, stream>>>(gmax, sf, augs, nn, nnT, num);
  bden_kernel<<<192, 256, 0, stream>>>(augs, nnT, bden);
  queue_kernel<<<B_ROWS, 256, 0, stream>>>(gps, sgps, sf, nn, qden);
  loss_kernel<<<1, 256, 0, stream>>>(num, bden, qden, out);
}

// Round 2
// 403.288 us; speedup vs baseline: 1.0746x; 1.0605x over previous
//
#include <hip/hip_runtime.h>
#include <hip/hip_bf16.h>

#define B_ROWS 256
#define S_SUP  65536
#define D_DIM  768
#define QSZ    512
#define NCHUNK 24          // 768 / 32
#define ACH 16384          // A chunk: 256 rows * 32 k * 2 B (bf16, swizzled)
#define BCH 8192           // B chunk: 64 cols * 32 k * 4 B (fp32, swizzled)

typedef short bf16x8 __attribute__((ext_vector_type(8)));
typedef float f32x4  __attribute__((ext_vector_type(4)));

__device__ __forceinline__ bf16x8 cvt8(float4 a, float4 b) {
  bf16x8 r;
  r[0] = (short)(__float_as_uint(a.x) >> 16);
  r[1] = (short)(__float_as_uint(a.y) >> 16);
  r[2] = (short)(__float_as_uint(a.z) >> 16);
  r[3] = (short)(__float_as_uint(a.w) >> 16);
  r[4] = (short)(__float_as_uint(b.x) >> 16);
  r[5] = (short)(__float_as_uint(b.y) >> 16);
  r[6] = (short)(__float_as_uint(b.z) >> 16);
  r[7] = (short)(__float_as_uint(b.w) >> 16);
  return r;
}

__device__ __forceinline__ void gl_lds16(const void* g, void* l) {
  __builtin_amdgcn_global_load_lds(
      (const __attribute__((address_space(1))) unsigned int*)g,
      (__attribute__((address_space(3))) unsigned int*)l, 16, 0, 0);
}

// block-wide sum (float), result broadcast to all 256 threads (4 waves)
__device__ __forceinline__ float block_sum(float v) {
  __shared__ float tmp[4];
  #pragma unroll
  for (int m = 32; m >= 1; m >>= 1) v += __shfl_xor(v, m, 64);
  __syncthreads();
  if ((threadIdx.x & 63) == 0) tmp[threadIdx.x >> 6] = v;
  __syncthreads();
  return tmp[0] + tmp[1] + tmp[2] + tmp[3];
}

__device__ __forceinline__ double block_sum_d(double v) {
  __shared__ double tmp[4];
  #pragma unroll
  for (int m = 32; m >= 1; m >>= 1) v += __shfl_xor(v, m, 64);
  __syncthreads();
  if ((threadIdx.x & 63) == 0) tmp[threadIdx.x >> 6] = v;
  __syncthreads();
  return tmp[0] + tmp[1] + tmp[2] + tmp[3];
}

// ---- kernel 0: zero accumulators ----
__global__ __launch_bounds__(256) void init_kernel(unsigned long long* gmax, double* bden) {
  int t = threadIdx.x;
  gmax[t] = 0ull;
  for (int i = t; i < 3 * B_ROWS; i += 256) bden[i] = 0.0;
}

// ---- kernel 1: augs[j-1] = normalize(V[j]*L); j==0 -> org_bf16 (swizzled chunk image) ----
// org_bf16 layout: chunk c (k in [32c,32c+32)) is a 16 KB image. Row r has 4 16B-groups
// (jg = (k&31)>>3); group jg stored at slot (jg ^ ((r>>1)&3)).
// ushort index = c*8192 + r*32 + slot*8 + (k&7).
__global__ __launch_bounds__(256) void prep_kernel(const float* __restrict__ V,
                                                   const float* __restrict__ L,
                                                   unsigned short* __restrict__ orgb,
                                                   float* __restrict__ augs) {
  int jb = blockIdx.x;            // 0..1023
  int j = jb >> 8, b = jb & 255;
  int tid = threadIdx.x;
  const float* v = V + ((size_t)j * B_ROWS + b) * D_DIM;
  const float* l = L + (size_t)b * D_DIM;
  float p[3]; float ssq = 0.f;
  #pragma unroll
  for (int i = 0; i < 3; ++i) {
    int k = tid + 256 * i;
    p[i] = v[k] * l[k];
    ssq += p[i] * p[i];
  }
  ssq = block_sum(ssq);
  float inv = 1.0f / fmaxf(sqrtf(ssq), 1e-12f);
  if (j == 0) {
    #pragma unroll
    for (int i = 0; i < 3; ++i) {
      int k = tid + 256 * i;
      unsigned short hv = (unsigned short)(__float_as_uint(p[i] * inv) >> 16);
      int c = k >> 5, jg = (k >> 3) & 3, e = k & 7;
      int slot = jg ^ ((b >> 1) & 3);
      orgb[c * 8192 + b * 32 + slot * 8 + e] = hv;
    }
  } else {
    float* dst = augs + ((size_t)(j - 1) * B_ROWS + b) * D_DIM;
    #pragma unroll
    for (int i = 0; i < 3; ++i) dst[tid + 256 * i] = p[i] * inv;
  }
}

// ---- kernel 2: sim = org @ sf^T (bf16 MFMA), per-row argmax ----
// 512 threads = 8 waves: wr = w>>1 (64-row band), wc = w&1 (32-col band).
// 24 k-chunks of 32; LDS = 24 KB -> 4 blocks/CU at VGPR<=64 => 32 waves/CU, grid
// exactly all-resident (1024 blocks / 256 CU). Conditional atomicMax epilogue.
__global__ __launch_bounds__(512, 8) void sim_argmax_kernel(const unsigned short* __restrict__ orgb,
                                                            const float* __restrict__ sf,
                                                            unsigned long long* __restrict__ gmax) {
  const int tid  = threadIdx.x;
  const int w    = tid >> 6;          // wave 0..7
  const int lid  = tid & 63;
  const int quad = lid >> 4;          // 0..3
  const int r15  = lid & 15;          // 0..15
  const int wr   = w >> 1;            // 0..3: rows 64*wr..+64
  const int wc   = w & 1;             // 0..1: cols 32*wc..+32
  const int s0   = blockIdx.x * 64;

  __shared__ __align__(16) char smem[ACH + BCH];   // 24 KB

  f32x4 acc[8];                       // [t*2+n]: t row-tile 0..3, n col-tile 0..1
  #pragma unroll
  for (int t = 0; t < 8; ++t) acc[t] = (f32x4){0.f, 0.f, 0.f, 0.f};

  // loop-invariant staging addresses
  const char* abase_g = (const char*)orgb + w * 1024 + lid * 16;
  {
  }
  // B source: thread stages group p=tid: row s=p>>3, slot=p&7 holds group gi=slot^(s&7)
  const int bs   = tid >> 3;
  const int gi   = (tid & 7) ^ (bs & 7);
  const float* bbase_g = sf + (size_t)(s0 + bs) * D_DIM + gi * 4;
  char* a_dst0 = smem + w * 1024;
  char* a_dst1 = smem + 8192 + w * 1024;
  char* b_dst  = smem + ACH + w * 1024;

  // read-side constants
  const int m7    = r15 & 7;
  const int aslot = (quad ^ ((r15 >> 1) & 3)) << 4;
  const char* arow = smem + (64 * wr + r15) * 64 + aslot;
  const char* brow0 = smem + ACH + (wc * 32 + r15) * 128;       // n=0
  const char* brow1 = brow0 + 16 * 128;                          // n=1
  const int gg = quad * 2;
  const int bo0 = ((gg    ) ^ m7) << 4;
  const int bo1 = ((gg + 1) ^ m7) << 4;

  for (int c = 0; c < NCHUNK; ++c) {
    // stage A chunk (16 KB): 2 gl_lds per thread, linear copy
    {
      const char* g = abase_g + c * ACH;
      gl_lds16(g,        a_dst0);
      gl_lds16(g + 8192, a_dst1);
    }
    // stage B chunk (8 KB): 1 gl_lds per thread, source pre-swizzled
    gl_lds16(bbase_g + c * 32, b_dst);
    __syncthreads();

    float4 p0 = *(const float4*)(brow0 + bo0);
    float4 p1 = *(const float4*)(brow0 + bo1);
    bf16x8 bf0 = cvt8(p0, p1);
    float4 q0 = *(const float4*)(brow1 + bo0);
    float4 q1 = *(const float4*)(brow1 + bo1);
    bf16x8 bf1 = cvt8(q0, q1);
    #pragma unroll
    for (int t = 0; t < 4; ++t) {
      bf16x8 af = *(const bf16x8*)(arow + t * 1024);
      acc[t * 2 + 0] = __builtin_amdgcn_mfma_f32_16x16x32_bf16(af, bf0, acc[t * 2 + 0], 0, 0, 0);
      acc[t * 2 + 1] = __builtin_amdgcn_mfma_f32_16x16x32_bf16(af, bf1, acc[t * 2 + 1], 0, 0, 0);
    }
    __syncthreads();
  }

  // epilogue: overlay reduction arrays on smem (tiles dead after final barrier)
  float* smax = (float*)smem;            // 8 waves * 64 rows
  int*   sidx = (int*)(smem + 2048);
  #pragma unroll
  for (int t = 0; t < 4; ++t) {
    #pragma unroll
    for (int r = 0; r < 4; ++r) {
      float bv; int bi;
      #pragma unroll
      for (int n = 0; n < 2; ++n) {
        float v = acc[t * 2 + n][r];
        int idx = s0 + wc * 32 + n * 16 + r15;
        #pragma unroll
        for (int m = 1; m < 16; m <<= 1) {   // reduce over 16 n-lanes
          float ov = __shfl_xor(v, m, 64);
          int   oi = __shfl_xor(idx, m, 64);
          if (ov > v || (ov == v && oi < idx)) { v = ov; idx = oi; }
        }
        if (n == 0) { bv = v; bi = idx; }
        else if (v > bv || (v == bv && idx < bi)) { bv = v; bi = idx; }
      }
      if (r15 == 0) {
        int local = 16 * t + 4 * quad + r;   // 0..63 within the wr band
        smax[w * 64 + local] = bv;
        sidx[w * 64 + local] = bi;
      }
    }
  }
  __syncthreads();
  if (tid < 256) {
    int b = tid;
    int wrb = b >> 6, local = b & 63;
    float v  = smax[(wrb * 2) * 64 + local];
    int  idx = sidx[(wrb * 2) * 64 + local];
    float ov = smax[(wrb * 2 + 1) * 64 + local];
    int   oi = sidx[(wrb * 2 + 1) * 64 + local];
    if (ov > v || (ov == v && oi < idx)) { v = ov; idx = oi; }
    unsigned u = __float_as_uint(v);
    unsigned key = (u & 0x80000000u) ? ~u : (u | 0x80000000u);
    unsigned long long packed = ((unsigned long long)key << 32) |
                                (unsigned long long)(0xFFFFFFFFu - (unsigned)idx);
    // conditional atomic: stale read only causes extra atomics, never missed ones
    if (packed > gmax[b]) atomicMax(gmax + b, packed);
  }
}

// ---- kernel 3: nn = normalize(sf[nn_idx]); nnT; num = dot(nn, augs[0][b]) / T ----
__global__ __launch_bounds__(256) void nn_kernel(const unsigned long long* __restrict__ gmax,
                                                 const float* __restrict__ sf,
                                                 const float* __restrict__ augs,
                                                 float* __restrict__ nn,
                                                 float* __restrict__ nnT,
                                                 float* __restrict__ num) {
  int b = blockIdx.x, tid = threadIdx.x;
  int idx = (int)(0xFFFFFFFFu - (unsigned)(gmax[b] & 0xFFFFFFFFull));
  const float* row = sf + (size_t)idx * D_DIM;
  float p[3]; float ssq = 0.f;
  #pragma unroll
  for (int i = 0; i < 3; ++i) { p[i] = row[tid + 256 * i]; ssq += p[i] * p[i]; }
  ssq = block_sum(ssq);
  float inv = 1.0f / fmaxf(sqrtf(ssq), 1e-12f);
  const float* a0 = augs + (size_t)b * D_DIM;    // augs[0][b]
  float dot = 0.f;
  #pragma unroll
  for (int i = 0; i < 3; ++i) {
    int k = tid + 256 * i;
    float nv = p[i] * inv;
    nn[(size_t)b * D_DIM + k] = nv;
    nnT[(size_t)k * B_ROWS + b] = nv;
    dot += nv * a0[k];
  }
  dot = block_sum(dot);
  if (tid == 0) num[b] = dot * 10.0f;            // 1/TEMP = 10
}

// ---- kernel 4: batch_den[j][b] += sum_i exp(10*dot(nn_b, aug_ji)) (double acc) ----
__global__ __launch_bounds__(256) void bden_kernel(const float* __restrict__ augs,
                                                   const float* __restrict__ nnT,
                                                   double* __restrict__ bden) {
  int jc = blockIdx.x;                 // 0..191
  int j = jc >> 6, c = jc & 63;
  int i0 = c * 4;
  __shared__ float s_aug[4 * D_DIM];
  const float* src = augs + ((size_t)j * B_ROWS + i0) * D_DIM;
  for (int idx = threadIdx.x; idx < 4 * D_DIM; idx += 256) s_aug[idx] = src[idx];
  __syncthreads();
  int b = threadIdx.x;
  float a0 = 0.f, a1 = 0.f, a2 = 0.f, a3 = 0.f;
  for (int k = 0; k < D_DIM; ++k) {
    float nv = nnT[(size_t)k * B_ROWS + b];
    a0 += nv * s_aug[k];
    a1 += nv * s_aug[D_DIM + k];
    a2 += nv * s_aug[2 * D_DIM + k];
    a3 += nv * s_aug[3 * D_DIM + k];
  }
  double v = exp((double)a0 * 10.0) + exp((double)a1 * 10.0) +
             exp((double)a2 * 10.0) + exp((double)a3 * 10.0);
  atomicAdd(&bden[j * B_ROWS + b], v);
}

// ---- kernel 5: GPS-filtered queue denominator (16 lanes per row, double exp-sum) ----
__global__ __launch_bounds__(256) void queue_kernel(const float* __restrict__ gps,
                                                    const float* __restrict__ sgps,
                                                    const float* __restrict__ sf,
                                                    const float* __restrict__ nn,
                                                    double* __restrict__ qden) {
  int b = blockIdx.x, tid = threadIdx.x;
  int w = tid >> 6, lane = tid & 63;
  __shared__ int qidx[QSZ];
  __shared__ int s_count;
  __shared__ int s_wcnt[4];
  __shared__ __align__(16) float s_nn[D_DIM];
  __shared__ double s_gsum[16];
  for (int k = tid; k < D_DIM; k += 256) s_nn[k] = nn[(size_t)b * D_DIM + k];
  if (tid == 0) s_count = 0;
  __syncthreads();

  const float r = 0.017453292519943295f;
  float lat1 = gps[b * 2 + 0] * r, lon1 = gps[b * 2 + 1] * r;
  float cl1 = cosf(lat1);
  int base = 0;
  while (true) {
    int count = s_count;
    if (count >= QSZ || base >= S_SUP) break;
    int s = base + tid;
    float lat2 = sgps[s * 2 + 0] * r, lon2 = sgps[s * 2 + 1] * r;
    float sdlat = sinf((lat2 - lat1) * 0.5f);
    float sdlon = sinf((lon2 - lon1) * 0.5f);
    float a = sdlat * sdlat + cl1 * cosf(lat2) * sdlon * sdlon;
    a = fminf(fmaxf(a, 0.f), 1.f);
    float d = 2.0f * 6371.0088f * asinf(sqrtf(a));
    bool valid = d > 25.0f;

    unsigned long long m = __ballot(valid);
    int wc = __popcll(m);
    if (lane == 0) s_wcnt[w] = wc;
    __syncthreads();
    int wbase = count;
    for (int i = 0; i < w; ++i) wbase += s_wcnt[i];
    int pos = wbase + __popcll(m & ((1ull << lane) - 1ull));
    if (valid && pos < QSZ) qidx[pos] = s;
    __syncthreads();
    if (tid == 0) {
      int total = s_wcnt[0] + s_wcnt[1] + s_wcnt[2] + s_wcnt[3];
      s_count = min(QSZ, count + total);
    }
    base += 256;
    __syncthreads();
  }
  int count = s_count;

  // phase 2: 16 lanes per row, 16 rows in flight per block
  int g  = lane >> 4;                  // group 0..3 within wave
  int l2 = lane & 15;
  double acc = 0.0;
  const float4* nn4 = (const float4*)s_nn;
  for (int q = w * 4 + g; q < count; q += 16) {
    const float4* row = (const float4*)(sf + (size_t)qidx[q] * D_DIM);
    float dot = 0.f;
    #pragma unroll
    for (int i = 0; i < 12; ++i) {
      float4 a = row[l2 + 16 * i];
      float4 nv = nn4[l2 + 16 * i];
      dot += a.x * nv.x + a.y * nv.y + a.z * nv.z + a.w * nv.w;
    }
    #pragma unroll
    for (int m2 = 8; m2 >= 1; m2 >>= 1) dot += __shfl_xor(dot, m2, 16);
    if (l2 == 0) acc += exp((double)dot * 10.0);
  }
  if (l2 == 0) s_gsum[w * 4 + g] = acc;
  __syncthreads();
  if (tid == 0) {
    double t = (double)(QSZ - count);
    #pragma unroll
    for (int i = 0; i < 16; ++i) t += s_gsum[i];
    qden[b] = t;
  }
}

// ---- kernel 6: final scalar loss (double) ----
__global__ __launch_bounds__(256) void loss_kernel(const float* __restrict__ num,
                                                   const double* __restrict__ bden,
                                                   const double* __restrict__ qden,
                                                   float* __restrict__ out) {
  int b = threadIdx.x;
  double q = qden[b];
  double n = (double)num[b];
  double t = 0.0;
  #pragma unroll
  for (int j = 0; j < 3; ++j) t += n - log(bden[j * B_ROWS + b] + q);
  t = block_sum_d(t);
  if (b == 0) out[0] = (float)(-t / 256.0);
}

extern "C" void kernel_launch(void* const* d_in, const int* in_sizes, int n_in,
                              void* d_out, int out_size, void* d_ws, size_t ws_size,
                              hipStream_t stream) {
  const float* V    = (const float*)d_in[0];   // (4,256,768)
  const float* L    = (const float*)d_in[1];   // (256,768)
  const float* gps  = (const float*)d_in[2];   // (256,2)
  const float* sf   = (const float*)d_in[3];   // (65536,768)
  const float* sgps = (const float*)d_in[4];   // (65536,2)
  float* out = (float*)d_out;

  char* ws = (char*)d_ws;
  size_t off = 0;
  unsigned short* orgb = (unsigned short*)(ws + off); off += 393216;  // 24*16KB bf16 swizzled
  float* augs = (float*)(ws + off); off += 2359296;                   // 3*256*768*4
  float* nn   = (float*)(ws + off); off += 786432;
  float* nnT  = (float*)(ws + off); off += 786432;
  float* num  = (float*)(ws + off); off += 1024;                      // 256*4
  double* bden = (double*)(ws + off); off += 6144;                    // 3*256*8
  double* qden = (double*)(ws + off); off += 2048;                    // 256*8
  unsigned long long* gmax = (unsigned long long*)(ws + off); off += 2048;

  init_kernel<<<1, 256, 0, stream>>>(gmax, bden);
  prep_kernel<<<1024, 256, 0, stream>>>(V, L, orgb, augs);
  sim_argmax_kernel<<<S_SUP / 64, 512, 0, stream>>>(orgb, sf, gmax);
  nn_kernel<<<B_ROWS, 256, 0, stream>>>(gmax, sf, augs, nn, nnT, num);
  bden_kernel<<<192, 256, 0, stream>>>(augs, nnT, bden);
  queue_kernel<<<B_ROWS, 256, 0, stream>>>(gps, sgps, sf, nn, qden);
  loss_kernel<<<1, 256, 0, stream>>>(num, bden, qden, out);
}

// Round 4
// 394.400 us; speedup vs baseline: 1.0988x; 1.0225x over previous
//
#include <hip/hip_runtime.h>
#include <hip/hip_bf16.h>

#define B_ROWS 256
#define S_SUP  65536
#define D_DIM  768
#define QSZ    512
#define NCH    12          // 768 / 64
#define ABYTES 32768       // A chunk: 256 rows * 64 k * 2 B bf16, k-group-major image
#define BBYTES 16384       // B tile: 128 cols * 64 k * 2 B bf16 (built in-kernel)

typedef short bf16x8 __attribute__((ext_vector_type(8)));
typedef float f32x4  __attribute__((ext_vector_type(4)));
typedef float f32x16 __attribute__((ext_vector_type(16)));

__device__ __forceinline__ bf16x8 cvt8(float4 a, float4 b) {
  bf16x8 r;
  r[0] = (short)(__float_as_uint(a.x) >> 16);
  r[1] = (short)(__float_as_uint(a.y) >> 16);
  r[2] = (short)(__float_as_uint(a.z) >> 16);
  r[3] = (short)(__float_as_uint(a.w) >> 16);
  r[4] = (short)(__float_as_uint(b.x) >> 16);
  r[5] = (short)(__float_as_uint(b.y) >> 16);
  r[6] = (short)(__float_as_uint(b.z) >> 16);
  r[7] = (short)(__float_as_uint(b.w) >> 16);
  return r;
}

__device__ __forceinline__ void gl_lds16(const void* g, void* l) {
  __builtin_amdgcn_global_load_lds(
      (const __attribute__((address_space(1))) unsigned int*)g,
      (__attribute__((address_space(3))) unsigned int*)l, 16, 0, 0);
}

// block-wide sum (float), result broadcast to all 256 threads (4 waves)
__device__ __forceinline__ float block_sum(float v) {
  __shared__ float tmp[4];
  #pragma unroll
  for (int m = 32; m >= 1; m >>= 1) v += __shfl_xor(v, m, 64);
  __syncthreads();
  if ((threadIdx.x & 63) == 0) tmp[threadIdx.x >> 6] = v;
  __syncthreads();
  return tmp[0] + tmp[1] + tmp[2] + tmp[3];
}

__device__ __forceinline__ double block_sum_d(double v) {
  __shared__ double tmp[4];
  #pragma unroll
  for (int m = 32; m >= 1; m >>= 1) v += __shfl_xor(v, m, 64);
  __syncthreads();
  if ((threadIdx.x & 63) == 0) tmp[threadIdx.x >> 6] = v;
  __syncthreads();
  return tmp[0] + tmp[1] + tmp[2] + tmp[3];
}

// ---- kernel 0: zero accumulators ----
__global__ __launch_bounds__(256) void init_kernel(unsigned long long* gmax, double* bden) {
  int t = threadIdx.x;
  gmax[t] = 0ull;
  for (int i = t; i < 3 * B_ROWS; i += 256) bden[i] = 0.0;
}

// ---- kernel 1: augs[j-1] = normalize(V[j]*L); j==0 -> org_bf16 image ----
// A image, chunk c (k in [64c,64c+64)): 32 KB, k-group-major:
// ushort idx = c*16384 + g*2048 + r*8 + e, where g=(k>>3)&7, e=k&7.
// Read banks: 16 consecutive rows per quarter-wave -> 2-way (free).
__global__ __launch_bounds__(256) void prep_kernel(const float* __restrict__ V,
                                                   const float* __restrict__ L,
                                                   unsigned short* __restrict__ orgb,
                                                   float* __restrict__ augs) {
  int jb = blockIdx.x;            // 0..1023
  int j = jb >> 8, b = jb & 255;
  int tid = threadIdx.x;
  __shared__ float srow[D_DIM];
  const float* v = V + ((size_t)j * B_ROWS + b) * D_DIM;
  const float* l = L + (size_t)b * D_DIM;
  float p[3]; float ssq = 0.f;
  #pragma unroll
  for (int i = 0; i < 3; ++i) {
    int k = tid + 256 * i;
    p[i] = v[k] * l[k];
    ssq += p[i] * p[i];
  }
  ssq = block_sum(ssq);
  float inv = 1.0f / fmaxf(sqrtf(ssq), 1e-12f);
  if (j == 0) {
    #pragma unroll
    for (int i = 0; i < 3; ++i) srow[tid + 256 * i] = p[i] * inv;
    __syncthreads();
    if (tid < 96) {                       // 96 groups of 8 k
      int k0 = tid * 8;
      float4 f0 = *(const float4*)&srow[k0];
      float4 f1 = *(const float4*)&srow[k0 + 4];
      bf16x8 hv = cvt8(f0, f1);
      int c = k0 >> 6, g = (k0 >> 3) & 7;
      *(bf16x8*)(orgb + c * 16384 + g * 2048 + b * 8) = hv;
    }
  } else {
    float* dst = augs + ((size_t)(j - 1) * B_ROWS + b) * D_DIM;
    #pragma unroll
    for (int i = 0; i < 3; ++i) dst[tid + 256 * i] = p[i] * inv;
  }
}

// ---- kernel 2: sim = org @ sf^T (bf16 MFMA 32x32x16), per-row argmax ----
// 512 threads = 8 waves (wr = w>>1 row-band of 64, wc = w&1 col-band of 64).
// Block tile 256x128, BK=64, 12 chunks. LDS 48 KB -> 2 blocks/CU, grid 512 = 2/CU.
// A: gl_lds verbatim copy of k-group-major image. B: reg-staged fp32->bf16,
// slot = s ^ g XOR swizzle (2-way banks on write and read).
__global__ __launch_bounds__(512, 4) void sim_argmax_kernel(const unsigned short* __restrict__ orgb,
                                                            const float* __restrict__ sf,
                                                            unsigned long long* __restrict__ gmax) {
  const int tid = threadIdx.x;
  const int w   = tid >> 6;           // wave 0..7
  const int l   = tid & 63;
  const int h   = l >> 5;             // half 0/1
  const int c31 = l & 31;
  const int wr  = w >> 1;             // row band (64 rows)
  const int wc  = w & 1;              // col band (64 cols)
  const int s0  = blockIdx.x * 128;

  __shared__ __align__(16) char smem[ABYTES + BBYTES];   // 48 KB

  f32x16 acc[4];                      // [t*2+n]
  #pragma unroll
  for (int t = 0; t < 4; ++t)
    #pragma unroll
    for (int r = 0; r < 16; ++r) acc[t][r] = 0.f;

  // B staging assignment: thread -> (col bs, k-offset ko), 64 B contiguous global
  const int bs = tid >> 2;            // 0..127
  const int ko = (tid & 3) * 16;      // 0,16,32,48
  const float* bsrc0 = sf + (size_t)(s0 + bs) * D_DIM + ko;
  const int g0 = ko >> 3;             // 0,2,4,6
  char* bw0 = smem + ABYTES + g0 * 2048 + ((bs ^ g0) & 127) * 16;
  char* bw1 = smem + ABYTES + (g0 + 1) * 2048 + ((bs ^ (g0 + 1)) & 127) * 16;

  // A staging: verbatim 32 KB copy, 4 x 1KB-per-wave insts
  const char* agbase = (const char*)orgb + w * 1024 + l * 16;
  char* aldst0 = smem + 0 * 8192 + w * 1024;
  char* aldst1 = smem + 1 * 8192 + w * 1024;
  char* aldst2 = smem + 2 * 8192 + w * 1024;
  char* aldst3 = smem + 3 * 8192 + w * 1024;

  // read-side row/col constants
  const int ar0 = wr * 64 + c31;       // t=0 row
  const int ar1 = ar0 + 32;            // t=1 row
  const int bs0 = wc * 64 + c31;       // n=0 col
  const int bs1 = bs0 + 32;            // n=1 col

  for (int c = 0; c < NCH; ++c) {
    // issue B global loads (coalesced 256B per 4 threads)
    const float4* bp = (const float4*)(bsrc0 + c * 64);
    float4 f0 = bp[0], f1 = bp[1], f2 = bp[2], f3 = bp[3];
    // issue A gl_lds (independent of B regs)
    {
      const char* g = agbase + c * ABYTES;
      gl_lds16(g,         aldst0);
      gl_lds16(g +  8192, aldst1);
      gl_lds16(g + 16384, aldst2);
      gl_lds16(g + 24576, aldst3);
    }
    // convert + LDS write B (waits only on f0..f3)
    *(bf16x8*)bw0 = cvt8(f0, f1);
    *(bf16x8*)bw1 = cvt8(f2, f3);
    __syncthreads();

    #pragma unroll
    for (int ks = 0; ks < 4; ++ks) {
      int g = ks * 2 + h;
      bf16x8 a0 = *(const bf16x8*)(smem + g * 4096 + ar0 * 16);
      bf16x8 a1 = *(const bf16x8*)(smem + g * 4096 + ar1 * 16);
      bf16x8 b0 = *(const bf16x8*)(smem + ABYTES + g * 2048 + ((bs0 ^ g) & 127) * 16);
      bf16x8 b1 = *(const bf16x8*)(smem + ABYTES + g * 2048 + ((bs1 ^ g) & 127) * 16);
      acc[0] = __builtin_amdgcn_mfma_f32_32x32x16_bf16(a0, b0, acc[0], 0, 0, 0);
      acc[1] = __builtin_amdgcn_mfma_f32_32x32x16_bf16(a0, b1, acc[1], 0, 0, 0);
      acc[2] = __builtin_amdgcn_mfma_f32_32x32x16_bf16(a1, b0, acc[2], 0, 0, 0);
      acc[3] = __builtin_amdgcn_mfma_f32_32x32x16_bf16(a1, b1, acc[3], 0, 0, 0);
    }
    __syncthreads();
  }

  // epilogue: overlay reduction arrays on smem (tiles dead after final barrier)
  float* smax = (float*)smem;            // [2][256]
  int*   sidx = (int*)(smem + 2048);
  #pragma unroll
  for (int t = 0; t < 2; ++t) {
    #pragma unroll
    for (int rg = 0; rg < 16; ++rg) {
      float v0 = acc[t * 2 + 0][rg];
      float v1 = acc[t * 2 + 1][rg];
      int i0 = s0 + wc * 64 + c31;
      int i1 = i0 + 32;
      float v; int idx;
      if (v1 > v0) { v = v1; idx = i1; } else { v = v0; idx = i0; }
      #pragma unroll
      for (int m = 1; m < 32; m <<= 1) {   // reduce over 32 col-lanes (stays in half)
        float ov = __shfl_xor(v, m, 64);
        int   oi = __shfl_xor(idx, m, 64);
        if (ov > v || (ov == v && oi < idx)) { v = ov; idx = oi; }
      }
      if (c31 == 0) {
        int row = wr * 64 + t * 32 + (rg & 3) + 8 * (rg >> 2) + 4 * h;  // C/D: m74/m101
        smax[wc * 256 + row] = v;
        sidx[wc * 256 + row] = idx;
      }
    }
  }
  __syncthreads();
  if (tid < 256) {
    int b = tid;
    float v  = smax[b];       int idx = sidx[b];
    float ov = smax[256 + b]; int oi  = sidx[256 + b];
    if (ov > v || (ov == v && oi < idx)) { v = ov; idx = oi; }
    unsigned u = __float_as_uint(v);
    unsigned key = (u & 0x80000000u) ? ~u : (u | 0x80000000u);
    unsigned long long packed = ((unsigned long long)key << 32) |
                                (unsigned long long)(0xFFFFFFFFu - (unsigned)idx);
    if (packed > gmax[b]) atomicMax(gmax + b, packed);   // conditional: stale read safe
  }
}

// ---- kernel 3: nn = normalize(sf[nn_idx]); nnT; num = dot(nn, augs[0][b]) / T ----
__global__ __launch_bounds__(256) void nn_kernel(const unsigned long long* __restrict__ gmax,
                                                 const float* __restrict__ sf,
                                                 const float* __restrict__ augs,
                                                 float* __restrict__ nn,
                                                 float* __restrict__ nnT,
                                                 float* __restrict__ num) {
  int b = blockIdx.x, tid = threadIdx.x;
  int idx = (int)(0xFFFFFFFFu - (unsigned)(gmax[b] & 0xFFFFFFFFull));
  const float* row = sf + (size_t)idx * D_DIM;
  float p[3]; float ssq = 0.f;
  #pragma unroll
  for (int i = 0; i < 3; ++i) { p[i] = row[tid + 256 * i]; ssq += p[i] * p[i]; }
  ssq = block_sum(ssq);
  float inv = 1.0f / fmaxf(sqrtf(ssq), 1e-12f);
  const float* a0 = augs + (size_t)b * D_DIM;    // augs[0][b]
  float dot = 0.f;
  #pragma unroll
  for (int i = 0; i < 3; ++i) {
    int k = tid + 256 * i;
    float nv = p[i] * inv;
    nn[(size_t)b * D_DIM + k] = nv;
    nnT[(size_t)k * B_ROWS + b] = nv;
    dot += nv * a0[k];
  }
  dot = block_sum(dot);
  if (tid == 0) num[b] = dot * 10.0f;            // 1/TEMP = 10
}

// ---- kernel 4: batch_den[j][b] += sum_i exp(10*dot(nn_b, aug_ji)) (double acc) ----
__global__ __launch_bounds__(256) void bden_kernel(const float* __restrict__ augs,
                                                   const float* __restrict__ nnT,
                                                   double* __restrict__ bden) {
  int jc = blockIdx.x;                 // 0..191
  int j = jc >> 6, c = jc & 63;
  int i0 = c * 4;
  __shared__ float s_aug[4 * D_DIM];
  const float* src = augs + ((size_t)j * B_ROWS + i0) * D_DIM;
  for (int idx = threadIdx.x; idx < 4 * D_DIM; idx += 256) s_aug[idx] = src[idx];
  __syncthreads();
  int b = threadIdx.x;
  float a0 = 0.f, a1 = 0.f, a2 = 0.f, a3 = 0.f;
  for (int k = 0; k < D_DIM; ++k) {
    float nv = nnT[(size_t)k * B_ROWS + b];
    a0 += nv * s_aug[k];
    a1 += nv * s_aug[D_DIM + k];
    a2 += nv * s_aug[2 * D_DIM + k];
    a3 += nv * s_aug[3 * D_DIM + k];
  }
  double v = exp((double)a0 * 10.0) + exp((double)a1 * 10.0) +
             exp((double)a2 * 10.0) + exp((double)a3 * 10.0);
  atomicAdd(&bden[j * B_ROWS + b], v);
}

// ---- kernel 5: GPS-filtered queue denominator (16 lanes per row, double exp-sum) ----
__global__ __launch_bounds__(256) void queue_kernel(const float* __restrict__ gps,
                                                    const float* __restrict__ sgps,
                                                    const float* __restrict__ sf,
                                                    const float* __restrict__ nn,
                                                    double* __restrict__ qden) {
  int b = blockIdx.x, tid = threadIdx.x;
  int w = tid >> 6, lane = tid & 63;
  __shared__ int qidx[QSZ];
  __shared__ int s_count;
  __shared__ int s_wcnt[4];
  __shared__ __align__(16) float s_nn[D_DIM];
  __shared__ double s_gsum[16];
  for (int k = tid; k < D_DIM; k += 256) s_nn[k] = nn[(size_t)b * D_DIM + k];
  if (tid == 0) s_count = 0;
  __syncthreads();

  const float r = 0.017453292519943295f;
  float lat1 = gps[b * 2 + 0] * r, lon1 = gps[b * 2 + 1] * r;
  float cl1 = cosf(lat1);
  int base = 0;
  while (true) {
    int count = s_count;
    if (count >= QSZ || base >= S_SUP) break;
    int s = base + tid;
    float lat2 = sgps[s * 2 + 0] * r, lon2 = sgps[s * 2 + 1] * r;
    float sdlat = sinf((lat2 - lat1) * 0.5f);
    float sdlon = sinf((lon2 - lon1) * 0.5f);
    float a = sdlat * sdlat + cl1 * cosf(lat2) * sdlon * sdlon;
    a = fminf(fmaxf(a, 0.f), 1.f);
    float d = 2.0f * 6371.0088f * asinf(sqrtf(a));
    bool valid = d > 25.0f;

    unsigned long long m = __ballot(valid);
    int wcnt = __popcll(m);
    if (lane == 0) s_wcnt[w] = wcnt;
    __syncthreads();
    int wbase = count;
    for (int i = 0; i < w; ++i) wbase += s_wcnt[i];
    int pos = wbase + __popcll(m & ((1ull << lane) - 1ull));
    if (valid && pos < QSZ) qidx[pos] = s;
    __syncthreads();
    if (tid == 0) {
      int total = s_wcnt[0] + s_wcnt[1] + s_wcnt[2] + s_wcnt[3];
      s_count = min(QSZ, count + total);
    }
    base += 256;
    __syncthreads();
  }
  int count = s_count;

  // phase 2: 16 lanes per row, 16 rows in flight per block
  int g  = lane >> 4;                  // group 0..3 within wave
  int l2 = lane & 15;
  double acc = 0.0;
  const float4* nn4 = (const float4*)s_nn;
  for (int q = w * 4 + g; q < count; q += 16) {
    const float4* row = (const float4*)(sf + (size_t)qidx[q] * D_DIM);
    float dot = 0.f;
    #pragma unroll
    for (int i = 0; i < 12; ++i) {
      float4 a = row[l2 + 16 * i];
      float4 nv = nn4[l2 + 16 * i];
      dot += a.x * nv.x + a.y * nv.y + a.z * nv.z + a.w * nv.w;
    }
    #pragma unroll
    for (int m2 = 8; m2 >= 1; m2 >>= 1) dot += __shfl_xor(dot, m2, 16);
    if (l2 == 0) acc += exp((double)dot * 10.0);
  }
  if (l2 == 0) s_gsum[w * 4 + g] = acc;
  __syncthreads();
  if (tid == 0) {
    double t = (double)(QSZ - count);
    #pragma unroll
    for (int i = 0; i < 16; ++i) t += s_gsum[i];
    qden[b] = t;
  }
}

// ---- kernel 6: final scalar loss (double) ----
__global__ __launch_bounds__(256) void loss_kernel(const float* __restrict__ num,
                                                   const double* __restrict__ bden,
                                                   const double* __restrict__ qden,
                                                   float* __restrict__ out) {
  int b = threadIdx.x;
  double q = qden[b];
  double n = (double)num[b];
  double t = 0.0;
  #pragma unroll
  for (int j = 0; j < 3; ++j) t += n - log(bden[j * B_ROWS + b] + q);
  t = block_sum_d(t);
  if (b == 0) out[0] = (float)(-t / 256.0);
}

extern "C" void kernel_launch(void* const* d_in, const int* in_sizes, int n_in,
                              void* d_out, int out_size, void* d_ws, size_t ws_size,
                              hipStream_t stream) {
  const float* V    = (const float*)d_in[0];   // (4,256,768)
  const float* L    = (const float*)d_in[1];   // (256,768)
  const float* gps  = (const float*)d_in[2];   // (256,2)
  const float* sf   = (const float*)d_in[3];   // (65536,768)
  const float* sgps = (const float*)d_in[4];   // (65536,2)
  float* out = (float*)d_out;

  char* ws = (char*)d_ws;
  size_t off = 0;
  unsigned short* orgb = (unsigned short*)(ws + off); off += 393216;  // 12*32KB bf16 image
  float* augs = (float*)(ws + off); off += 2359296;                   // 3*256*768*4
  float* nn   = (float*)(ws + off); off += 786432;
  float* nnT  = (float*)(ws + off); off += 786432;
  float* num  = (float*)(ws + off); off += 1024;                      // 256*4
  double* bden = (double*)(ws + off); off += 6144;                    // 3*256*8
  double* qden = (double*)(ws + off); off += 2048;                    // 256*8
  unsigned long long* gmax = (unsigned long long*)(ws + off); off += 2048;

  init_kernel<<<1, 256, 0, stream>>>(gmax, bden);
  prep_kernel<<<1024, 256, 0, stream>>>(V, L, orgb, augs);
  sim_argmax_kernel<<<S_SUP / 128, 512, 0, stream>>>(orgb, sf, gmax);
  nn_kernel<<<B_ROWS, 256, 0, stream>>>(gmax, sf, augs, nn, nnT, num);
  bden_kernel<<<192, 256, 0, stream>>>(augs, nnT, bden);
  queue_kernel<<<B_ROWS, 256, 0, stream>>>(gps, sgps, sf, nn, qden);
  loss_kernel<<<1, 256, 0, stream>>>(num, bden, qden, out);
}